// Round 3
// baseline (153.731 us; speedup 1.0000x reference)
//
#include <hip/hip_runtime.h>

#define NB 4
#define NC 64
#define NH 256
#define NW 256
#define TH 16                  // output rows per block (4 waves x 4 rows)
#define SROWS (TH + 6)         // 22 staged input rows (incl. +/-3 halo)
#define LROW 264               // LDS row: 4 zero-pad | 256 data | 4 zero-pad

// ---------- phase 1: per-pixel weight params, shared by all 64 channels ----------
__global__ __launch_bounds__(256)
void wprep(const float* __restrict__ persp,
           const float* __restrict__ alpha_p,
           const float* __restrict__ beta_p,
           const float* __restrict__ gamma_p,
           float* __restrict__ ws)
{
    const float alpha = alpha_p[0];
    const float beta  = beta_p[0];
    const float gamma = gamma_p[0];
    const int i = (blockIdx.x * 256 + threadIdx.x) * 4;
    const float4 p = *(const float4*)(persp + i);
    const float pa[4] = {p.x, p.y, p.z, p.w};
    float g[4], inv2[4];
    #pragma unroll
    for (int k = 0; k < 4; ++k) {
        const float z  = fmaf(beta, pa[k], gamma);
        const float sg = __builtin_amdgcn_rcpf(1.0f + __expf(-z));
        const float sigma = fmaxf(alpha * sg, 1e-4f);
        const float t  = 0.5f * __builtin_amdgcn_rcpf(sigma * sigma);
        const float gg = __expf(-t);
        const float g2 = gg * gg;
        const float p4 = g2 * g2;
        const float p9 = p4 * p4 * gg;
        const float S  = fmaf(2.0f, (gg + p4) + p9, 1.0f);
        const float inv = __builtin_amdgcn_rcpf(S);
        g[k] = gg;
        inv2[k] = inv * inv;
    }
    float* wp = ws + (size_t)i * 2;
    *(float4*)(wp)     = make_float4(g[0], inv2[0], g[1], inv2[1]);
    *(float4*)(wp + 4) = make_float4(g[2], inv2[2], g[3], inv2[3]);
}

// ---------- phase 2: row-major pair pass, no register window ----------
// Round-2 lesson: a 7x12 register window NEVER fits (VGPR=84 + AGPR overflow
// -> 2 waves/SIMD, VALUBusy 30%). This version's live set is ~110 short-lived
// scalars; expect VGPR 110-140, no AGPR traffic, 4 waves/SIMD.
__global__ __launch_bounds__(256, 2)
void adaptive_gauss7(const float* __restrict__ x,
                     const float* __restrict__ wsr,
                     float* __restrict__ out)
{
    __shared__ float lds[SROWS * LROW];   // 23,232 B

    const int tid  = threadIdx.x;
    const int lane = tid & 63;
    const int wv   = tid >> 6;            // 4 waves x 4 rows = 16 rows
    const int c    = blockIdx.x;
    const int h0   = blockIdx.y * TH;
    const int b    = blockIdx.z;
    const int colbase = lane * 4;         // output cols colbase..colbase+3
    const int rg      = h0 + wv * 4;      // first output row of this wave

    const float* xc   = x   + (size_t)(b * NC + c) * NH * NW;
    float*       outp = out + (size_t)(b * NC + c) * NH * NW;
    const float* wrow = wsr + (size_t)b * NH * NW * 2;

    // (1) issue ws loads for all 4 output rows NOW — they complete while the
    //     staging DMA drains at the barrier (free latency hiding)
    float4 wsv[8];
    #pragma unroll
    for (int o = 0; o < 4; ++o) {
        const float* wp = wrow + ((size_t)(rg + o) * NW + colbase) * 2;   // lane*32B, coalesced
        wsv[2 * o]     = *(const float4*)(wp);       // {g0,i0,g1,i1}
        wsv[2 * o + 1] = *(const float4*)(wp + 4);   // {g2,i2,g3,i3}
    }

    // (2) side pads: zero 4 floats at both ends of each staged row
    if (tid < SROWS) {
        *(float4*)&lds[tid * LROW]       = make_float4(0.f, 0.f, 0.f, 0.f);
        *(float4*)&lds[tid * LROW + 260] = make_float4(0.f, 0.f, 0.f, 0.f);
    }

    // (3) async stage: wave-interleaved rows, DMA straight to LDS
    for (int r = wv; r < SROWS; r += 4) {
        const int gr = h0 - 3 + r;                     // wave-uniform bound
        if ((unsigned)gr < NH) {
            __builtin_amdgcn_global_load_lds(
                (const __attribute__((address_space(1))) void*)(xc + (size_t)gr * NW + colbase),
                (__attribute__((address_space(3))) void*)&lds[r * LROW + 4],
                16, 0, 0);
        } else {
            *(float4*)&lds[r * LROW + 4 + colbase] = make_float4(0.f, 0.f, 0.f, 0.f);
        }
    }
    __syncthreads();

    // (4) compute: two output rows at a time; each of 8 input rows read ONCE
    #pragma unroll
    for (int half = 0; half < 2; ++half) {
        const int o0 = 2 * half;
        const float4 wa0 = wsv[2 * o0],     wb0 = wsv[2 * o0 + 1];
        const float4 wa1 = wsv[2 * o0 + 2], wb1 = wsv[2 * o0 + 3];
        const float g0_[4] = {wa0.x, wa0.z, wb0.x, wb0.z};
        const float i0_[4] = {wa0.y, wa0.w, wb0.y, wb0.w};
        const float g1_[4] = {wa1.x, wa1.z, wb1.x, wb1.z};
        const float i1_[4] = {wa1.y, wa1.w, wb1.y, wb1.w};
        float g0[4], p40[4], p90[4], g1[4], p41[4], p91[4];
        #pragma unroll
        for (int k = 0; k < 4; ++k) {
            g0[k] = g0_[k];
            const float t = g0[k] * g0[k];
            p40[k] = t * t;
            p90[k] = p40[k] * p40[k] * g0[k];
            g1[k] = g1_[k];
            const float u = g1[k] * g1[k];
            p41[k] = u * u;
            p91[k] = p41[k] * p41[k] * g1[k];
        }

        // pair-sum slots: s*_0 = rs0+rs6, s*_1 = rs1+rs5, s*_2 = rs2+rs4, s*_3 = rs3
        float s0_0[4], s0_1[4], s0_2[4], s0_3[4];
        float s1_0[4], s1_1[4], s1_2[4], s1_3[4];

        #pragma unroll
        for (int r = 0; r < 8; ++r) {
            const float* rp = &lds[(wv * 4 + o0 + r) * LROW + colbase]; // cols colbase-4..+7
            const float4 a0 = *(const float4*)(rp);
            const float4 a1 = *(const float4*)(rp + 4);
            const float4 a2 = *(const float4*)(rp + 8);
            const float w[12] = {a0.x, a0.y, a0.z, a0.w,
                                 a1.x, a1.y, a1.z, a1.w,
                                 a2.x, a2.y, a2.z, a2.w};
            #pragma unroll
            for (int k = 0; k < 4; ++k) {
                if (r < 7) {                           // tap j = r for row o0
                    const float rs = fmaf(p90[k], w[k + 1] + w[k + 7],
                                     fmaf(p40[k], w[k + 2] + w[k + 6],
                                     fmaf(g0[k],  w[k + 3] + w[k + 5],
                                                  w[k + 4])));
                    if      (r == 0) s0_0[k] = rs;
                    else if (r == 1) s0_1[k] = rs;
                    else if (r == 2) s0_2[k] = rs;
                    else if (r == 3) s0_3[k] = rs;
                    else if (r == 4) s0_2[k] = s0_2[k] + rs;
                    else if (r == 5) s0_1[k] = s0_1[k] + rs;
                    else             s0_0[k] = s0_0[k] + rs;
                }
                if (r >= 1) {                          // tap j = r-1 for row o0+1
                    const float rs = fmaf(p91[k], w[k + 1] + w[k + 7],
                                     fmaf(p41[k], w[k + 2] + w[k + 6],
                                     fmaf(g1[k],  w[k + 3] + w[k + 5],
                                                  w[k + 4])));
                    const int j = r - 1;
                    if      (j == 0) s1_0[k] = rs;
                    else if (j == 1) s1_1[k] = rs;
                    else if (j == 2) s1_2[k] = rs;
                    else if (j == 3) s1_3[k] = rs;
                    else if (j == 4) s1_2[k] = s1_2[k] + rs;
                    else if (j == 5) s1_1[k] = s1_1[k] + rs;
                    else             s1_0[k] = s1_0[k] + rs;
                }
            }
        }

        // vertical combine — exact association of rounds 0-2 (same absmax)
        float res0[4], res1[4];
        #pragma unroll
        for (int k = 0; k < 4; ++k) {
            res0[k] = fmaf(p90[k], s0_0[k],
                      fmaf(p40[k], s0_1[k],
                      fmaf(g0[k],  s0_2[k], s0_3[k]))) * i0_[k];
            res1[k] = fmaf(p91[k], s1_0[k],
                      fmaf(p41[k], s1_1[k],
                      fmaf(g1[k],  s1_2[k], s1_3[k]))) * i1_[k];
        }
        *(float4*)(outp + (size_t)(rg + o0) * NW + colbase) =
            make_float4(res0[0], res0[1], res0[2], res0[3]);
        *(float4*)(outp + (size_t)(rg + o0 + 1) * NW + colbase) =
            make_float4(res1[0], res1[1], res1[2], res1[3]);
    }
}

extern "C" void kernel_launch(void* const* d_in, const int* in_sizes, int n_in,
                              void* d_out, int out_size, void* d_ws, size_t ws_size,
                              hipStream_t stream) {
    const float* x     = (const float*)d_in[0];
    const float* persp = (const float*)d_in[1];
    const float* alpha = (const float*)d_in[2];
    const float* beta  = (const float*)d_in[3];
    const float* gamma = (const float*)d_in[4];
    float* outp        = (float*)d_out;
    float* ws          = (float*)d_ws;       // 4*256*256*2 floats = 2 MiB

    wprep<<<dim3((NB * NH * NW) / 1024), dim3(256), 0, stream>>>(persp, alpha, beta, gamma, ws);
    adaptive_gauss7<<<dim3(NC, NH / TH, NB), dim3(256), 0, stream>>>(x, ws, outp);
}